// Round 11
// baseline (45.665 us; speedup 1.0000x reference)
//
#include <hip/hip_runtime.h>

// 5x5 median, reflect padding, NHWC f32 (16,384,384,3).
// STATELESS decomposition (R1's pattern, which hit 94% VALUBusy, + R2-R9's
// validated math): one thread = one vertical OUTPUT PAIR (h, h+1) at one flat
// column f. No loop-carried ring -> no serialized schedule; all 30 tap loads
// are independent and issued up-front (max memory-level parallelism).
//   - 6 rows (h-2..h+3) x 5 stride-3 taps; interior taps are constant offsets
//     {-6,-3,0,3,6} off a single base (no column reflect math).
//   - 6 SORT5 row sorts; outputs share 4 of 6 rows -> MED25_PAIR computes the
//     per-column SORT4 of common rows ONCE, each output rank-inserts its
//     private row (closed forms), then forgetful rank-7-of-13. [R2-R9]
// Border columns (flat 0..5, 1146..1151) in dedicated trailing blocks.

#define CAS(a, b) do { float _t = fminf(a, b); (b) = fmaxf(a, b); (a) = _t; } while (0)

#define SORT5(e0, e1, e2, e3, e4) do { \
  CAS(e0, e1); CAS(e3, e4); CAS(e2, e4); CAS(e2, e3); CAS(e1, e4); \
  CAS(e0, e3); CAS(e0, e2); CAS(e1, e3); CAS(e1, e2); } while (0)

#define SORT4(a, b, c, d) do { \
  CAS(a, b); CAS(c, d); CAS(a, c); CAS(b, d); CAS(b, c); } while (0)

__device__ __forceinline__ int reflect_idx(int v, int n) {
  v = v < 0 ? -v : v;
  v = v >= n ? 2 * n - 2 - v : v;
  return v;
}

#define SORT_TO(P, e0, e1, e2, e3, e4) do { \
  SORT5(e0, e1, e2, e3, e4); \
  P##0 = e0; P##1 = e1; P##2 = e2; P##3 = e3; P##4 = e4; } while (0)

// Rank-7-of-13 band selection; consumes locals A1..E2 (mutating), writes dst.
#define BANDSEL(dst) do { \
  CAS(B3, Cx3); CAS(A1, B1); CAS(A1, Cx1); \
  CAS(A2, B3); CAS(Cx2, D2); CAS(B3, D2); \
  CAS(B1, Cx1); CAS(D1, A2); CAS(B1, D1); \
  float s0=Cx1,s1=B2,s2=B3,s3=Cx2,s4=A2,s5=D1,s6=D3,s7=E1; \
  CAS(s0, s1); CAS(s2, s3); CAS(s4, s5); CAS(s6, s7); \
  CAS(s0, s2); CAS(s4, s6); CAS(s0, s4); \
  CAS(s1, s3); CAS(s5, s7); CAS(s3, s7); \
  float t0=s1,t1=s2,t2=s3,t3=s4,t4=s5,t5=s6,t6=E2; \
  CAS(t0, t1); CAS(t2, t3); CAS(t4, t5); \
  CAS(t0, t2); CAS(t0, t4); CAS(t0, t6); \
  CAS(t1, t3); CAS(t5, t6); CAS(t3, t6); \
  CAS(t1, t2); CAS(t3, t4); \
  CAS(t1, t3); CAS(t1, t5); \
  CAS(t2, t4); CAS(t4, t5); \
  CAS(t2, t3); \
  dst = fmaxf(t2, fminf(t3, t4)); \
} while (0)

// Paired exact median-of-25: S0..S3 = the 4 COMMON sorted rows (any order),
// IA = first output's private sorted row, IB = second's. Shares the SORT4s.
#define MED25_PAIR(dA, dB, S0, S1, S2, S3, IA, IB) do { \
  float pp0=S0##0,qq0=S1##0,rr0=S2##0,ss0=S3##0; SORT4(pp0,qq0,rr0,ss0); \
  float pp1=S0##1,qq1=S1##1,rr1=S2##1,ss1=S3##1; SORT4(pp1,qq1,rr1,ss1); \
  float pp2=S0##2,qq2=S1##2,rr2=S2##2,ss2=S3##2; SORT4(pp2,qq2,rr2,ss2); \
  float pp3=S0##3,qq3=S1##3,rr3=S2##3,ss3=S3##3; SORT4(pp3,qq3,rr3,ss3); \
  float pp4=S0##4,qq4=S1##4,rr4=S2##4,ss4=S3##4; SORT4(pp4,qq4,rr4,ss4); \
  { float D1=fmaxf(rr0,fminf(ss0,IA##0)), E1=fmaxf(ss0,IA##0); \
    float Cx1=fmaxf(qq1,fminf(rr1,IA##1)), D2=fmaxf(rr1,fminf(ss1,IA##1)), E2=fmaxf(ss1,IA##1); \
    float B1=fmaxf(pp2,fminf(qq2,IA##2)), Cx2=fmaxf(qq2,fminf(rr2,IA##2)), D3=fmaxf(rr2,fminf(ss2,IA##2)); \
    float A1=fminf(pp3,IA##3), B2=fminf(qq3,fmaxf(pp3,IA##3)), Cx3=fminf(rr3,fmaxf(qq3,IA##3)); \
    float A2=fminf(pp4,IA##4), B3=fminf(qq4,fmaxf(pp4,IA##4)); \
    BANDSEL(dA); } \
  { float D1=fmaxf(rr0,fminf(ss0,IB##0)), E1=fmaxf(ss0,IB##0); \
    float Cx1=fmaxf(qq1,fminf(rr1,IB##1)), D2=fmaxf(rr1,fminf(ss1,IB##1)), E2=fmaxf(ss1,IB##1); \
    float B1=fmaxf(pp2,fminf(qq2,IB##2)), Cx2=fmaxf(qq2,fminf(rr2,IB##2)), D3=fmaxf(rr2,fminf(ss2,IB##2)); \
    float A1=fminf(pp3,IB##3), B2=fminf(qq3,fmaxf(pp3,IB##3)), Cx3=fminf(rr3,fmaxf(qq3,IB##3)); \
    float A2=fminf(pp4,IB##4), B3=fminf(qq4,fmaxf(pp4,IB##4)); \
    BANDSEL(dB); } \
} while (0)

constexpr int Bn = 16, Hn = 384, Wn = 384, Cn = 3;
constexpr int WC = Wn * Cn;               // 1152
constexpr int HP = Hn / 2;                // 192 vertical output pairs
constexpr int NF_I = 1140;                // interior flat cols: f = 6 + gi
constexpr int N_INT = Bn * HP * NF_I;     // 3,502,080 = 13,680 * 256
constexpr int N_BND = Bn * HP * 12;       // 36,864   = 144 * 256

__global__ __launch_bounds__(256) void median5x5_kernel(
    const float* __restrict__ x, float* __restrict__ out) {
  int t = blockIdx.x * blockDim.x + threadIdx.x;

  if (t < N_INT) {
    // ---------------- interior: stateless output-pair ----------------
    int gi = t % NF_I;
    int rest = t / NF_I;
    int hp = rest % HP;
    int b = rest / HP;
    int h = 2 * hp;
    int f = 6 + gi;                        // f in [6,1146): taps f-6..f+6 valid

    const float* xb = x + b * Hn * WC + f;

    // sorted 5-windows for rows h-2 .. h+3
    float r00,r01,r02,r03,r04, r10,r11,r12,r13,r14, r20,r21,r22,r23,r24,
          r30,r31,r32,r33,r34, r40,r41,r42,r43,r44, r50,r51,r52,r53,r54;

#define LOADSORT(RN, RR) do { \
    const float* rp = xb + reflect_idx((RR), Hn) * WC; \
    float e0 = rp[-6], e1 = rp[-3], e2 = rp[0], e3 = rp[3], e4 = rp[6]; \
    SORT_TO(RN, e0, e1, e2, e3, e4); } while (0)

    LOADSORT(r0, h - 2);
    LOADSORT(r1, h - 1);
    LOADSORT(r2, h    );
    LOADSORT(r3, h + 1);
    LOADSORT(r4, h + 2);
    LOADSORT(r5, h + 3);

    // output h uses rows r0..r4; output h+1 uses r1..r5; common r1..r4
    float oA, oB;
    MED25_PAIR(oA, oB, r1, r2, r3, r4, r0, r5);

    int o = (b * Hn + h) * WC + f;
    out[o]      = oA;
    out[o + WC] = oB;
  } else {
    // ---------------- border columns (w reflection) ----------------
    int u = t - N_INT;
    int col = u % 12;
    int rest = u / 12;
    int hp = rest % HP;
    int b = rest / HP;
    int h = 2 * hp;
    int f = col < 6 ? col : (1140 + col);  // 0..5 or 1146..1151
    int w = f / 3, c = f % 3;

    int o0 = reflect_idx(w - 2, Wn) * 3 + c;
    int o1 = reflect_idx(w - 1, Wn) * 3 + c;
    int o2 = w * 3 + c;
    int o3 = reflect_idx(w + 1, Wn) * 3 + c;
    int o4 = reflect_idx(w + 2, Wn) * 3 + c;

    const float* xb = x + b * Hn * WC;

    float r00,r01,r02,r03,r04, r10,r11,r12,r13,r14, r20,r21,r22,r23,r24,
          r30,r31,r32,r33,r34, r40,r41,r42,r43,r44, r50,r51,r52,r53,r54;

#define BLOADSORT(RN, RR) do { \
    const float* rp = xb + reflect_idx((RR), Hn) * WC; \
    float e0 = rp[o0], e1 = rp[o1], e2 = rp[o2], e3 = rp[o3], e4 = rp[o4]; \
    SORT_TO(RN, e0, e1, e2, e3, e4); } while (0)

    BLOADSORT(r0, h - 2);
    BLOADSORT(r1, h - 1);
    BLOADSORT(r2, h    );
    BLOADSORT(r3, h + 1);
    BLOADSORT(r4, h + 2);
    BLOADSORT(r5, h + 3);

    float oA, oB;
    MED25_PAIR(oA, oB, r1, r2, r3, r4, r0, r5);

    int o = (b * Hn + h) * WC + f;
    out[o]      = oA;
    out[o + WC] = oB;
  }
}

extern "C" void kernel_launch(void* const* d_in, const int* in_sizes, int n_in,
                              void* d_out, int out_size, void* d_ws, size_t ws_size,
                              hipStream_t stream) {
  const float* x = (const float*)d_in[0];
  float* out = (float*)d_out;
  int total_threads = N_INT + N_BND;        // 3,538,944 = 13,824 * 256 exactly
  int block = 256;
  int grid = total_threads / block;         // 13,824
  median5x5_kernel<<<grid, block, 0, stream>>>(x, out);
}

// Round 12
// 33.125 us; speedup vs baseline: 1.3786x; 1.3786x over previous
//
#include <hip/hip_runtime.h>

// 5x5 median, reflect padding, NHWC f32 (16,384,384,3).
// R9 structure (best: 38.5us): thread = 2 flat cols x RUN=6 rows, 3 paired
// phases, 6-slot ring of sorted 5-windows, 7xfloat2 loads/row.
// R12 change: 3-input ALU ops (v_med3/min3/max3, full-rate) replace 2-op
// patterns wherever the network's sortedness invariants make them exact:
//   - rank-insert cells: fmax(lo,fmin(hi,e)) == med3(lo,hi,e) when lo<=hi
//   - SORT3 = {min3,med3,max3}; SORT4 = SORT3+4-inst insert (7 vs 10);
//     SORT5 = SORT4+5-inst insert (12 vs 18)
//   - BANDSEL tail: median of 3 survivors = one med3
// Math per pair ~234 -> ~185 lane-ops. [band selection validated R2-R11]

#define MIN3(a, b, c) fminf(fminf(a, b), c)
#define MAX3(a, b, c) fmaxf(fmaxf(a, b), c)
#define MED3(a, b, c) __builtin_amdgcn_fmed3f((a), (b), (c))

#define CAS(a, b) do { float _t = fminf(a, b); (b) = fmaxf(a, b); (a) = _t; } while (0)

// SORT3 via 3-input ops: 3 insts.
#define SORT3M(a, b, c) do { \
  float _lo = MIN3(a, b, c), _mi = MED3(a, b, c), _hi = MAX3(a, b, c); \
  (a) = _lo; (b) = _mi; (c) = _hi; } while (0)

// Insert d into sorted (a<=b<=c): 4 insts.
#define SORT4M(a, b, c, d) do { \
  SORT3M(a, b, c); \
  float _n0 = fminf(a, d), _n1 = MED3(a, b, d), _n2 = MED3(b, c, d), _n3 = fmaxf(c, d); \
  (a) = _n0; (b) = _n1; (c) = _n2; (d) = _n3; } while (0)

// Insert e into sorted (a<=b<=c<=d): 5 insts. SORT5 total = 12 insts.
#define SORT5M(a, b, c, d, e) do { \
  SORT4M(a, b, c, d); \
  float _m0 = fminf(a, e), _m1 = MED3(a, b, e), _m2 = MED3(b, c, e), \
        _m3 = MED3(c, d, e), _m4 = fmaxf(d, e); \
  (a) = _m0; (b) = _m1; (c) = _m2; (d) = _m3; (e) = _m4; } while (0)

__device__ __forceinline__ int reflect_idx(int v, int n) {
  v = v < 0 ? -v : v;
  v = v >= n ? 2 * n - 2 - v : v;
  return v;
}

#define SORT_TO(P, e0, e1, e2, e3, e4) do { \
  SORT5M(e0, e1, e2, e3, e4); \
  P##0 = e0; P##1 = e1; P##2 = e2; P##3 = e3; P##4 = e4; } while (0)

// Rank-7-of-13 band selection; consumes locals A1..E2 (mutating), writes dst.
// Tail: median of the 3 survivors = single med3.
#define BANDSEL(dst) do { \
  CAS(B3, Cx3); CAS(A1, B1); CAS(A1, Cx1); \
  CAS(A2, B3); CAS(Cx2, D2); CAS(B3, D2); \
  CAS(B1, Cx1); CAS(D1, A2); CAS(B1, D1); \
  float s0=Cx1,s1=B2,s2=B3,s3=Cx2,s4=A2,s5=D1,s6=D3,s7=E1; \
  CAS(s0, s1); CAS(s2, s3); CAS(s4, s5); CAS(s6, s7); \
  CAS(s0, s2); CAS(s4, s6); CAS(s0, s4); \
  CAS(s1, s3); CAS(s5, s7); CAS(s3, s7); \
  float t0=s1,t1=s2,t2=s3,t3=s4,t4=s5,t5=s6,t6=E2; \
  CAS(t0, t1); CAS(t2, t3); CAS(t4, t5); \
  CAS(t0, t2); CAS(t0, t4); CAS(t0, t6); \
  CAS(t1, t3); CAS(t5, t6); CAS(t3, t6); \
  CAS(t1, t2); CAS(t3, t4); \
  CAS(t1, t3); CAS(t1, t5); \
  CAS(t2, t4); CAS(t4, t5); \
  dst = MED3(t2, t3, t4); \
} while (0)

// Paired exact median-of-25: S0..S3 = the 4 COMMON sorted rows (any order),
// IA = first output's private sorted row, IB = second's. Shares the SORT4s.
// Insert cells: med3 forms exact under column sortedness (pp<=qq<=rr<=ss).
#define MED25_PAIR(dA, dB, S0, S1, S2, S3, IA, IB) do { \
  float pp0=S0##0,qq0=S1##0,rr0=S2##0,ss0=S3##0; SORT4M(pp0,qq0,rr0,ss0); \
  float pp1=S0##1,qq1=S1##1,rr1=S2##1,ss1=S3##1; SORT4M(pp1,qq1,rr1,ss1); \
  float pp2=S0##2,qq2=S1##2,rr2=S2##2,ss2=S3##2; SORT4M(pp2,qq2,rr2,ss2); \
  float pp3=S0##3,qq3=S1##3,rr3=S2##3,ss3=S3##3; SORT4M(pp3,qq3,rr3,ss3); \
  float pp4=S0##4,qq4=S1##4,rr4=S2##4,ss4=S3##4; SORT4M(pp4,qq4,rr4,ss4); \
  { float D1 = MED3(rr0, ss0, IA##0), E1 = fmaxf(ss0, IA##0); \
    float Cx1 = MED3(qq1, rr1, IA##1), D2 = MED3(rr1, ss1, IA##1), E2 = fmaxf(ss1, IA##1); \
    float B1 = MED3(pp2, qq2, IA##2), Cx2 = MED3(qq2, rr2, IA##2), D3 = MED3(rr2, ss2, IA##2); \
    float A1 = fminf(pp3, IA##3), B2 = MED3(pp3, qq3, IA##3), Cx3 = MED3(qq3, rr3, IA##3); \
    float A2 = fminf(pp4, IA##4), B3 = MED3(pp4, qq4, IA##4); \
    BANDSEL(dA); } \
  { float D1 = MED3(rr0, ss0, IB##0), E1 = fmaxf(ss0, IB##0); \
    float Cx1 = MED3(qq1, rr1, IB##1), D2 = MED3(rr1, ss1, IB##1), E2 = fmaxf(ss1, IB##1); \
    float B1 = MED3(pp2, qq2, IB##2), Cx2 = MED3(qq2, rr2, IB##2), D3 = MED3(rr2, ss2, IB##2); \
    float A1 = fminf(pp3, IB##3), B2 = MED3(pp3, qq3, IB##3), Cx3 = MED3(qq3, rr3, IB##3); \
    float A2 = fminf(pp4, IB##4), B3 = MED3(pp4, qq4, IB##4); \
    BANDSEL(dB); } \
} while (0)

constexpr int RUN = 6;
constexpr int Bn = 16, Hn = 384, Wn = 384, Cn = 3;
constexpr int WC = Wn * Cn;              // 1152
constexpr int HB = Hn / RUN;             // 64
constexpr int NG_I = 570;                // pairs (f, f+1), f = 6 + 2*gi
constexpr int N_INT = Bn * HB * NG_I;    // 583680 = 2280 * 256
constexpr int N_BND = Bn * HB * 12;      // 12288  = 48 * 256

// Load row RR (absolute h) into the 7 named float2 regs.
#define LOADROW(V0,V1,V2,V3,V4,V5,V6, RR) do { \
  const float2* rp = reinterpret_cast<const float2*>(xb + reflect_idx((RR), Hn) * WC); \
  V0=rp[0]; V1=rp[1]; V2=rp[2]; V3=rp[3]; V4=rp[4]; V5=rp[5]; V6=rp[6]; } while (0)

// Sort the 7-float2 raw row into ring slots PA (col f) / PB (col f+1).
#define SORTROW(V0,V1,V2,V3,V4,V5,V6, PA, PB) do { \
  float e0=V0.x,e1=V1.y,e2=V3.x,e3=V4.y,e4=V6.x; \
  float g0=V0.y,g1=V2.x,g2=V3.y,g3=V5.x,g4=V6.y; \
  SORT_TO(PA, e0, e1, e2, e3, e4); \
  SORT_TO(PB, g0, g1, g2, g3, g4); } while (0)

__global__ __launch_bounds__(256) void median5x5_kernel(
    const float* __restrict__ x, float* __restrict__ out) {
  int t = blockIdx.x * blockDim.x + threadIdx.x;

  if (t < N_INT) {
    // ---------------- interior fast path ----------------
    int gi = t % NG_I;
    int rest = t / NG_I;
    int hb = rest % HB;
    int b = rest / HB;
    int h0 = hb * RUN;
    int f = 6 + 2 * gi;

    const float* xb = x + b * Hn * WC + (f - 6);

    // 6-slot ring x 5 sorted elems x 2 cols; slot(r) = (r - h0 + 2) mod 6
    float a00,a01,a02,a03,a04, a10,a11,a12,a13,a14, a20,a21,a22,a23,a24,
          a30,a31,a32,a33,a34, a40,a41,a42,a43,a44, a50,a51,a52,a53,a54;
    float b00,b01,b02,b03,b04, b10,b11,b12,b13,b14, b20,b21,b22,b23,b24,
          b30,b31,b32,b33,b34, b40,b41,b42,b43,b44, b50,b51,b52,b53,b54;

    float2 v0, v1, v2, v3, v4, v5, v6;   // prefetch row A
    float2 u0, u1, u2, u3, u4, u5, u6;   // prefetch row B

    // prologue: rows h0-2..h0+1 -> slots 0..3
    LOADROW(v0,v1,v2,v3,v4,v5,v6, h0 - 2); SORTROW(v0,v1,v2,v3,v4,v5,v6, a0, b0);
    LOADROW(v0,v1,v2,v3,v4,v5,v6, h0 - 1); SORTROW(v0,v1,v2,v3,v4,v5,v6, a1, b1);
    LOADROW(v0,v1,v2,v3,v4,v5,v6, h0    ); SORTROW(v0,v1,v2,v3,v4,v5,v6, a2, b2);
    LOADROW(v0,v1,v2,v3,v4,v5,v6, h0 + 1); SORTROW(v0,v1,v2,v3,v4,v5,v6, a3, b3);

    // prefetch rows h0+2, h0+3
    LOADROW(v0,v1,v2,v3,v4,v5,v6, h0 + 2);
    LOADROW(u0,u1,u2,u3,u4,u5,u6, h0 + 3);

    int orow = (b * Hn + h0) * WC + f;

    // ---- phase 0: outputs h0, h0+1 ----
    SORTROW(v0,v1,v2,v3,v4,v5,v6, a4, b4);   // row h0+2 -> slot 4
    SORTROW(u0,u1,u2,u3,u4,u5,u6, a5, b5);   // row h0+3 -> slot 5
    LOADROW(v0,v1,v2,v3,v4,v5,v6, h0 + 4);
    LOADROW(u0,u1,u2,u3,u4,u5,u6, h0 + 5);
    {
      float2 oA, oB;
      MED25_PAIR(oA.x, oB.x, a1, a2, a3, a4, a0, a5);
      MED25_PAIR(oA.y, oB.y, b1, b2, b3, b4, b0, b5);
      *reinterpret_cast<float2*>(out + orow         ) = oA;
      *reinterpret_cast<float2*>(out + orow + 1 * WC) = oB;
    }

    // ---- phase 1: outputs h0+2, h0+3 ----
    SORTROW(v0,v1,v2,v3,v4,v5,v6, a0, b0);   // row h0+4 -> slot 0
    SORTROW(u0,u1,u2,u3,u4,u5,u6, a1, b1);   // row h0+5 -> slot 1
    LOADROW(v0,v1,v2,v3,v4,v5,v6, h0 + 6);
    LOADROW(u0,u1,u2,u3,u4,u5,u6, h0 + 7);
    {
      float2 oA, oB;
      MED25_PAIR(oA.x, oB.x, a3, a4, a5, a0, a2, a1);
      MED25_PAIR(oA.y, oB.y, b3, b4, b5, b0, b2, b1);
      *reinterpret_cast<float2*>(out + orow + 2 * WC) = oA;
      *reinterpret_cast<float2*>(out + orow + 3 * WC) = oB;
    }

    // ---- phase 2: outputs h0+4, h0+5 ----
    SORTROW(v0,v1,v2,v3,v4,v5,v6, a2, b2);   // row h0+6 -> slot 2
    SORTROW(u0,u1,u2,u3,u4,u5,u6, a3, b3);   // row h0+7 -> slot 3
    {
      float2 oA, oB;
      MED25_PAIR(oA.x, oB.x, a5, a0, a1, a2, a4, a3);
      MED25_PAIR(oA.y, oB.y, b5, b0, b1, b2, b4, b3);
      *reinterpret_cast<float2*>(out + orow + 4 * WC) = oA;
      *reinterpret_cast<float2*>(out + orow + 5 * WC) = oB;
    }
  } else {
    // ---------------- border columns (w reflection) ----------------
    int u = t - N_INT;
    int col = u % 12;
    int rest = u / 12;
    int hb = rest % HB;
    int b = rest / HB;
    int h0 = hb * RUN;
    int f = col < 6 ? col : (WC - 12 + col);   // 0..5 or 1146..1151
    int w = f / 3, c = f % 3;

    int o0 = reflect_idx(w - 2, Wn) * 3 + c;
    int o1 = reflect_idx(w - 1, Wn) * 3 + c;
    int o2 = w * 3 + c;
    int o3 = reflect_idx(w + 1, Wn) * 3 + c;
    int o4 = reflect_idx(w + 2, Wn) * 3 + c;

    const float* xb = x + b * Hn * WC;

    // 6-slot ring, single column
    float a00,a01,a02,a03,a04, a10,a11,a12,a13,a14, a20,a21,a22,a23,a24,
          a30,a31,a32,a33,a34, a40,a41,a42,a43,a44, a50,a51,a52,a53,a54;

#define BLOAD_SORT(RR, AN) do { \
    const float* rp = xb + reflect_idx((RR), Hn) * WC; \
    float e0=rp[o0], e1=rp[o1], e2=rp[o2], e3=rp[o3], e4=rp[o4]; \
    SORT_TO(AN, e0, e1, e2, e3, e4); } while (0)

    BLOAD_SORT(h0 - 2, a0); BLOAD_SORT(h0 - 1, a1);
    BLOAD_SORT(h0    , a2); BLOAD_SORT(h0 + 1, a3);

    int orow = (b * Hn + h0) * WC + f;

    // phase 0: rows h0+2,h0+3 -> slots 4,5
    BLOAD_SORT(h0 + 2, a4); BLOAD_SORT(h0 + 3, a5);
    {
      float oA, oB;
      MED25_PAIR(oA, oB, a1, a2, a3, a4, a0, a5);
      out[orow         ] = oA;
      out[orow + 1 * WC] = oB;
    }
    // phase 1: rows h0+4,h0+5 -> slots 0,1
    BLOAD_SORT(h0 + 4, a0); BLOAD_SORT(h0 + 5, a1);
    {
      float oA, oB;
      MED25_PAIR(oA, oB, a3, a4, a5, a0, a2, a1);
      out[orow + 2 * WC] = oA;
      out[orow + 3 * WC] = oB;
    }
    // phase 2: rows h0+6,h0+7 -> slots 2,3
    BLOAD_SORT(h0 + 6, a2); BLOAD_SORT(h0 + 7, a3);
    {
      float oA, oB;
      MED25_PAIR(oA, oB, a5, a0, a1, a2, a4, a3);
      out[orow + 4 * WC] = oA;
      out[orow + 5 * WC] = oB;
    }
  }
}

extern "C" void kernel_launch(void* const* d_in, const int* in_sizes, int n_in,
                              void* d_out, int out_size, void* d_ws, size_t ws_size,
                              hipStream_t stream) {
  const float* x = (const float*)d_in[0];
  float* out = (float*)d_out;
  int total_threads = N_INT + N_BND;        // 595968 = 2328 * 256 exactly
  int block = 256;
  int grid = total_threads / block;         // 2328
  median5x5_kernel<<<grid, block, 0, stream>>>(x, out);
}